// Round 9
// baseline (25.133 us; speedup 1.0000x reference)
//
#include <hip/hip_runtime.h>
#include <math.h>

#define BLOCK 512
#define WPB 8          // waves per block
#define NGRID 1000
#define HPAD 68        // sH row stride (floats): 272B, 16B-aligned
#define W4S 68         // sW4t row stride

// broadcast lane i's value to all lanes (uniform result, literal index)
__device__ __forceinline__ float rdl(float v, int i) {
    return __uint_as_float(__builtin_amdgcn_readlane(__float_as_uint(v), i));
}
__device__ __forceinline__ float frcp(float x) { return __builtin_amdgcn_rcpf(x); }
__device__ __forceinline__ float fsqrt(float x) { return __builtin_amdgcn_sqrtf(x); }

__global__ __launch_bounds__(BLOCK) void ph_kernel(
    const float* __restrict__ x,
    const float* __restrict__ W1, const float* __restrict__ b1,
    const float* __restrict__ W2, const float* __restrict__ b2,
    const float* __restrict__ W3, const float* __restrict__ b3,
    const float* __restrict__ W4, const float* __restrict__ b4,
    const float* __restrict__ kin,
    float* __restrict__ out, int B)
{
    // W2/W3 transposed + XOR-swizzled 16B granules (proven layout):
    // row j (output unit) holds column j of W; granule g stored at g^(j&7).
    __shared__ __attribute__((aligned(16))) float sW2t[64*64];
    __shared__ __attribute__((aligned(16))) float sW3t[64*64];
    __shared__ __attribute__((aligned(16))) float sW4t[6*W4S];
    __shared__ __attribute__((aligned(16))) float sH[WPB][2][HPAD];
    __shared__ float sB4[8];
    __shared__ float sLat[WPB][2][8];

    const int tid = threadIdx.x;

    for (int l = tid; l < 64*64; l += BLOCK) {
        const int i = l >> 6, j = l & 63;
        const int dst = (j << 6) + ((((i >> 2) ^ (j & 7)) << 2) | (i & 3));
        sW2t[dst] = W2[l];
        sW3t[dst] = W3[l];
    }
    for (int l = tid; l < 64*6; l += BLOCK) {
        const int i = l / 6, u = l - 6*i;
        sW4t[u*W4S + i] = W4[l];
    }
    if (tid < 8) sB4[tid] = (tid < 6) ? b4[tid] : 0.0f;
    __syncthreads();   // the only block-wide barrier

    const int lane = tid & 63;
    const int widx = tid >> 6;
    const int half = lane >> 5;
    const int la   = lane & 31;
    const int j    = lane;
    const int wbase = blockIdx.x * WPB + widx;
    const int wstride = gridDim.x * WPB;         // total waves in grid

    // loop-invariant per-lane weights/biases
    float w1r[5];
    #pragma unroll
    for (int i = 0; i < 5; ++i) w1r[i] = W1[(i << 6) + j];
    const float b1j = b1[j], b2j = b2[j], b3j = b3[j];
    const int swz = (j & 7) << 2;

    const float i00 = kin[0], i01 = kin[1], i02 = kin[2];
    const float invRT = 1.0f / 2478.8191f;
    const float ksr0 = ((-kin[3]) * 96485.33f) * invRT;
    const float ksr1 = ((-kin[4]) * 96485.33f) * invRT;
    const float ksr2 = ((-kin[5]) * 96485.33f) * invRT;
    const float stepV = 1.25f / 999.0f;
    const int xmax = B*5 - 1;

    // ---- grid-stride loop: same code re-executed -> hot I$ after pass 1 ----
    #pragma unroll 1
    for (int row0 = wbase*2; row0 < B; row0 += wstride*2) {

        // x for 2 rows via lanes 0..9 (clamped), distributed by readlane
        int xidx = row0*5 + lane;
        if (xidx > xmax) xidx = xmax;
        const float xv = x[xidx];

        // ---- layer 1: 5 -> 64, exact fma chain (bias first, i ascending) ----
        float h0 = b1j, h1 = b1j;
        #pragma unroll
        for (int i = 0; i < 5; ++i) {
            h0 = fmaf(rdl(xv, i    ), w1r[i], h0);
            h1 = fmaf(rdl(xv, 5 + i), w1r[i], h1);
        }
        h0 = fmaxf(h0, 0.0f); h1 = fmaxf(h1, 0.0f);

        // ---- layers 2,3: weights from LDS (16 b128/layer), h via readlane ----
        {
            const float* wrow = sW2t + (j << 6);
            float a0 = b2j, a1 = b2j;
            #pragma unroll
            for (int i4 = 0; i4 < 16; ++i4) {
                const float4 wv = *(const float4*)(wrow + (((i4 << 2) ^ swz)));
                const int i0 = i4 << 2;
                a0 = fmaf(rdl(h0, i0  ), wv.x, a0);
                a1 = fmaf(rdl(h1, i0  ), wv.x, a1);
                a0 = fmaf(rdl(h0, i0+1), wv.y, a0);
                a1 = fmaf(rdl(h1, i0+1), wv.y, a1);
                a0 = fmaf(rdl(h0, i0+2), wv.z, a0);
                a1 = fmaf(rdl(h1, i0+2), wv.z, a1);
                a0 = fmaf(rdl(h0, i0+3), wv.w, a0);
                a1 = fmaf(rdl(h1, i0+3), wv.w, a1);
            }
            h0 = fmaxf(a0, 0.0f); h1 = fmaxf(a1, 0.0f);
        }
        {
            const float* wrow = sW3t + (j << 6);
            float a0 = b3j, a1 = b3j;
            #pragma unroll
            for (int i4 = 0; i4 < 16; ++i4) {
                const float4 wv = *(const float4*)(wrow + (((i4 << 2) ^ swz)));
                const int i0 = i4 << 2;
                a0 = fmaf(rdl(h0, i0  ), wv.x, a0);
                a1 = fmaf(rdl(h1, i0  ), wv.x, a1);
                a0 = fmaf(rdl(h0, i0+1), wv.y, a0);
                a1 = fmaf(rdl(h1, i0+1), wv.y, a1);
                a0 = fmaf(rdl(h0, i0+2), wv.z, a0);
                a1 = fmaf(rdl(h1, i0+2), wv.z, a1);
                a0 = fmaf(rdl(h0, i0+3), wv.w, a0);
                a1 = fmaf(rdl(h1, i0+3), wv.w, a1);
            }
            h0 = fmaxf(a0, 0.0f); h1 = fmaxf(a1, 0.0f);
        }

        // ---- park h in LDS for layer 4 (same-wave write->read, in-order) ----
        sH[widx][0][j] = h0;
        sH[widx][1][j] = h1;

        // ---- layer 4: 64 -> 6, lanes 0..11 = (r = lane&1, u = lane>>1) ----
        if (lane < 12) {
            const int r = lane & 1, u = lane >> 1;
            const float* wrow = sW4t + u * W4S;
            const float* hrow = sH[widx][r];
            float acc = sB4[u];
            #pragma unroll
            for (int i4 = 0; i4 < 16; ++i4) {
                const float4 wv = *(const float4*)(wrow + (i4 << 2));
                const float4 hv = *(const float4*)(hrow + (i4 << 2));
                acc = fmaf(hv.x, wv.x, acc); acc = fmaf(hv.y, wv.y, acc);
                acc = fmaf(hv.z, wv.z, acc); acc = fmaf(hv.w, wv.w, acc);
            }
            sLat[widx][r][u] = acc;
        }

        const int row = row0 + half;
        const bool act = (row < B);

        // ---- physics: lanes {0,32} each run one row's chain ----
        float c0v = 0.0f, c1v = 0.0f, c2v = 0.0f, l0v = 0.0f, l1v = 0.0f;
        if (la == 0) {
            const int rowc = act ? row : (B - 1);
            const float* plat = sLat[widx][half];
            const float lat0 = plat[0], lat1 = plat[1], lat2 = plat[2];
            const float lat3 = plat[3], lat4 = plat[4], lat5 = plat[5];
            const float rr   = 4e-8f * __expf(lat0);
            const float epsv = frcp(1.0f + __expf(-lat1));
            const float zlt  = x[rowc*5 + 3];
            const float Lf   = zlt * frcp(1.0f - epsv);
            const float Kdl  = __expf(lat2);
            const float z0 = 2.0f*lat3, z1 = 2.0f*lat4, z2 = 2.0f*lat5;
            const float mz = fmaxf(z0, fmaxf(z1, z2));
            const float p0 = __expf(z0 - mz), p1 = __expf(z1 - mz), p2 = __expf(z2 - mz);
            const float ips = frcp(p0 + p1 + p2);
            const float th0 = p0*ips, th1 = p1*ips, th2 = p2*ips;
            const float irr = frcp(rr);
            const float gdl   = (Kdl * 1.91e-9f) * (epsv * fsqrt(epsv)) * irr;
            const float asurf = (3.0f * (1.0f - epsv)) * Lf * irr;
            c0v = (i00*th0)*asurf; c1v = (i01*th1)*asurf; c2v = (i02*th2)*asurf;
            const float il0 = (((2.0f*96485.33f)*34.0f)*gdl)*0.1f;
            const float il1 = (((12.0f*96485.33f)*34.0f)*gdl)*0.1f;
            l0v = frcp(il0); l1v = frcp(il1);
        }
        // broadcast row constants within each half (bit-exact)
        const int src = half << 5;
        const float c0    = __shfl(c0v, src, 64);
        const float c1    = __shfl(c1v, src, 64);
        const float c2    = __shfl(c2v, src, 64);
        const float invl0 = __shfl(l0v, src, 64);
        const float invl1 = __shfl(l1v, src, 64);

        auto evaltot = [&](int v) -> float {
            const float V = -1.25f + stepV * (float)v;
            const float t0 = __expf(ksr0 * (V + 0.11f));
            const float t1 = __expf(ksr1 * (V - 0.08f));
            const float t2 = __expf(ksr2 * V);
            const float ie0 = frcp(frcp(c0*t0) + invl0);
            const float ie1 = frcp(frcp(c1*t1) + invl1);
            const float ie2 = c2*t2;       // i_lim[2] = inf
            return ie0 + ie1 + ie2;
        };

        // coarse: 32 points stride 32; i_tot weakly decreasing in v
        const int vc = la << 5;            // 0..992
        const float totc = evaltot(vc);
        float bd = fabsf(totc - 200.0f);
        int bidx = vc;

        const unsigned long long mall = __ballot(totc >= 200.0f);
        const unsigned int m32 = (unsigned int)(mall >> (half << 5));
        const int kstar = m32 ? (31 - __builtin_clz(m32)) : 0;
        const int base = kstar << 5;

        // fine: 32 points (base, base+32]; coarse candidates cover the rest
        {
            int vf = base + 1 + la;
            if (vf > NGRID-1) vf = NGRID-1;
            const float totf = evaltot(vf);
            const float df = fabsf(totf - 200.0f);
            if (df < bd || (df == bd && vf < bidx)) { bd = df; bidx = vf; }
        }

        // lexicographic (d, idx) butterfly within each 32-lane half
        #pragma unroll
        for (int off = 16; off; off >>= 1) {
            const float od = __shfl_xor(bd, off, 64);
            const int   oi = __shfl_xor(bidx, off, 64);
            if (od < bd || (od == bd && oi < bidx)) { bd = od; bidx = oi; }
        }

        // ---- select + FE ----
        const float V = -1.25f + stepV * (float)bidx;
        const float t0 = __expf(ksr0 * (V + 0.11f));
        const float t1 = __expf(ksr1 * (V - 0.08f));
        const float t2 = __expf(ksr2 * V);
        const float ie0 = frcp(frcp(c0*t0) + invl0);
        const float ie1 = frcp(frcp(c1*t1) + invl1);
        const float ie2 = c2*t2;
        const float itr = frcp(ie0 + ie1 + ie2);
        if (act && la < 2) {
            out[row*2 + la] = (la == 0) ? (ie1*itr) : (ie0*itr);
        }
    }
}

extern "C" void kernel_launch(void* const* d_in, const int* in_sizes, int n_in,
                              void* d_out, int out_size, void* d_ws, size_t ws_size,
                              hipStream_t stream) {
    const float* x   = (const float*)d_in[0];
    const float* W1  = (const float*)d_in[1];
    const float* b1  = (const float*)d_in[2];
    const float* W2  = (const float*)d_in[3];
    const float* b2  = (const float*)d_in[4];
    const float* W3  = (const float*)d_in[5];
    const float* b3  = (const float*)d_in[6];
    const float* W4  = (const float*)d_in[7];
    const float* b4  = (const float*)d_in[8];
    const float* kin = (const float*)d_in[9];
    float* out = (float*)d_out;
    const int B = in_sizes[0] / 5;

    // grid-stride: 512 blocks x 8 waves x 2 rows = 8192 rows/pass -> 2 passes.
    // 2 blocks/CU (39.3 KB LDS), 16 waves/CU; pass 2 runs with hot I$.
    const int grid = 512;
    ph_kernel<<<grid, BLOCK, 0, stream>>>(x, W1, b1, W2, b2, W3, b3, W4, b4, kin, out, B);
}

// Round 11
// 18.005 us; speedup vs baseline: 1.3959x; 1.3959x over previous
//
#include <hip/hip_runtime.h>
#include <math.h>

#define NGRID 1000
#define BLOCK 256
#define WPB 4          // waves per block; each wave owns 16 rows -> 64 rows/block

typedef __attribute__((ext_vector_type(8))) __bf16 bf16x8;
typedef __attribute__((ext_vector_type(4))) float  f32x4;

__device__ __forceinline__ float frcp(float x)  { return __builtin_amdgcn_rcpf(x); }
__device__ __forceinline__ float fsqrt(float x) { return __builtin_amdgcn_sqrtf(x); }

#define MFMA16(A,Bv,C) __builtin_amdgcn_mfma_f32_16x16x32_bf16((A),(Bv),(C),0,0,0)

// split v into bf16 hi (RTNE cast) + bf16 lo (residual), by value
__device__ __forceinline__ __bf16 bhi(float v) { return (__bf16)v; }
__device__ __forceinline__ __bf16 blo(float v, __bf16 hi) {
    return (__bf16)(v - (float)hi);
}

__global__ __launch_bounds__(BLOCK) void ph_kernel(
    const float* __restrict__ x,
    const float* __restrict__ W1, const float* __restrict__ b1,
    const float* __restrict__ W2, const float* __restrict__ b2,
    const float* __restrict__ W3, const float* __restrict__ b3,
    const float* __restrict__ W4, const float* __restrict__ b4,
    const float* __restrict__ kin,
    float* __restrict__ out, int B)
{
    // weight fragments in MFMA-frag-ready order: [nt][kt][lane][e] -> b128/lane
    __shared__ __attribute__((aligned(16))) __bf16 sW1h[4][64][8],    sW1l[4][64][8];
    __shared__ __attribute__((aligned(16))) __bf16 sW2h[4][2][64][8], sW2l[4][2][64][8];
    __shared__ __attribute__((aligned(16))) __bf16 sW3h[4][2][64][8], sW3l[4][2][64][8];
    __shared__ __attribute__((aligned(16))) __bf16 sW4h[2][64][8],    sW4l[2][64][8];
    // h planes between layers: [local row][k], stride 72 (144B) kills b128 conflicts
    __shared__ __attribute__((aligned(16))) __bf16 sHh[64][72], sHl[64][72];
    __shared__ float sLat[WPB][16][8];

    const int tid  = threadIdx.x;
    const int lane = tid & 63;
    const int widx = tid >> 6;
    const int lr   = lane & 15;     // A-row / B-col / C-col within 16-tile
    const int kg   = lane >> 4;     // k-group (8 k's per group)
    const int r0   = blockIdx.x * 64 + widx * 16;   // wave's first row

    // ---- x fragments for layer 1 (before barrier; independent of LDS) ----
    // A[row=lr][k=kg*8+e], valid k<5 (kg==0, e<5)
    bf16x8 xh, xl;
    {
        int xrow = r0 + lr; if (xrow > B-1) xrow = B-1;
        #pragma unroll
        for (int e = 0; e < 8; ++e) {
            float v = 0.0f;
            if (kg == 0 && e < 5) v = x[xrow*5 + e];
            const __bf16 hi = bhi(v);
            xh[e] = hi;
            xl[e] = blo(v, hi);
        }
    }

    // ================= stage weight fragments (frag-ready layout) ==========
    {
        const int nt  = widx;            // each wave quarter handles one ntile
        const int col = nt*16 + lr;
        bf16x8 h8, l8;
        #pragma unroll
        for (int e = 0; e < 8; ++e) {
            const int k = kg*8 + e;
            float v = 0.0f;
            if (k < 5) v = W1[k*64 + col];
            const __bf16 hi = bhi(v);
            h8[e] = hi;
            l8[e] = blo(v, hi);
        }
        *(bf16x8*)&sW1h[nt][lane][0] = h8;
        *(bf16x8*)&sW1l[nt][lane][0] = l8;

        #pragma unroll
        for (int kt = 0; kt < 2; ++kt) {
            bf16x8 h2, l2, h3, l3;
            #pragma unroll
            for (int e = 0; e < 8; ++e) {
                const int k = kt*32 + kg*8 + e;
                const float v2 = W2[k*64 + col];
                const float v3 = W3[k*64 + col];
                const __bf16 hi2 = bhi(v2);
                const __bf16 hi3 = bhi(v3);
                h2[e] = hi2; l2[e] = blo(v2, hi2);
                h3[e] = hi3; l3[e] = blo(v3, hi3);
            }
            *(bf16x8*)&sW2h[nt][kt][lane][0] = h2;
            *(bf16x8*)&sW2l[nt][kt][lane][0] = l2;
            *(bf16x8*)&sW3h[nt][kt][lane][0] = h3;
            *(bf16x8*)&sW3l[nt][kt][lane][0] = l3;
        }
        if (widx == 0) {                 // W4 (64x6): ntile 0 only, cols>=6 zero
            #pragma unroll
            for (int kt = 0; kt < 2; ++kt) {
                bf16x8 h4, l4;
                #pragma unroll
                for (int e = 0; e < 8; ++e) {
                    const int k = kt*32 + kg*8 + e;
                    float v = 0.0f;
                    if (lr < 6) v = W4[k*6 + lr];
                    const __bf16 hi = bhi(v);
                    h4[e] = hi;
                    l4[e] = blo(v, hi);
                }
                *(bf16x8*)&sW4h[kt][lane][0] = h4;
                *(bf16x8*)&sW4l[kt][lane][0] = l4;
            }
        }
    }
    __syncthreads();   // the only block-wide barrier

    const f32x4 zz = {0.0f, 0.0f, 0.0f, 0.0f};
    f32x4 acc[4];

    // ================= layer 1: x(16x5 pad32) @ W1 =================
    #pragma unroll
    for (int nt = 0; nt < 4; ++nt) {
        const bf16x8 bh = *(const bf16x8*)&sW1h[nt][lane][0];
        const bf16x8 bl = *(const bf16x8*)&sW1l[nt][lane][0];
        f32x4 t = MFMA16(xl, bh, zz);
        t = MFMA16(xh, bl, t);
        acc[nt] = MFMA16(xh, bh, t);
    }
    // bias + ReLU + split -> h planes (wave-local rows; no barrier needed)
    #pragma unroll
    for (int nt = 0; nt < 4; ++nt) {
        const float bb = b1[nt*16 + lr];
        #pragma unroll
        for (int rg = 0; rg < 4; ++rg) {
            float v = fmaxf(acc[nt][rg] + bb, 0.0f);
            const int row = widx*16 + kg*4 + rg;
            const __bf16 hi = bhi(v);
            sHh[row][nt*16 + lr] = hi;
            sHl[row][nt*16 + lr] = blo(v, hi);
        }
    }

    // ================= layers 2,3: h(16x64) @ W =================
    #pragma unroll
    for (int L = 0; L < 2; ++L) {
        const int lrow = widx*16 + lr;
        bf16x8 ah[2], al[2];
        #pragma unroll
        for (int kt = 0; kt < 2; ++kt) {
            ah[kt] = *(const bf16x8*)&sHh[lrow][kt*32 + kg*8];
            al[kt] = *(const bf16x8*)&sHl[lrow][kt*32 + kg*8];
        }
        #pragma unroll
        for (int nt = 0; nt < 4; ++nt) {
            f32x4 t = zz;
            #pragma unroll
            for (int kt = 0; kt < 2; ++kt) {
                const bf16x8 bh = (L == 0) ? *(const bf16x8*)&sW2h[nt][kt][lane][0]
                                           : *(const bf16x8*)&sW3h[nt][kt][lane][0];
                const bf16x8 bl = (L == 0) ? *(const bf16x8*)&sW2l[nt][kt][lane][0]
                                           : *(const bf16x8*)&sW3l[nt][kt][lane][0];
                t = MFMA16(al[kt], bh, t);
                t = MFMA16(ah[kt], bl, t);
                t = MFMA16(ah[kt], bh, t);
            }
            acc[nt] = t;
        }
        const float* bp = (L == 0) ? b2 : b3;
        #pragma unroll
        for (int nt = 0; nt < 4; ++nt) {
            const float bb = bp[nt*16 + lr];
            #pragma unroll
            for (int rg = 0; rg < 4; ++rg) {
                float v = fmaxf(acc[nt][rg] + bb, 0.0f);
                const int row = widx*16 + kg*4 + rg;
                const __bf16 hi = bhi(v);
                sHh[row][nt*16 + lr] = hi;   // in-place: all reads already done
                sHl[row][nt*16 + lr] = blo(v, hi);
            }
        }
    }

    // ================= layer 4: h(16x64) @ W4 -> sLat =================
    {
        const int lrow = widx*16 + lr;
        f32x4 t = zz;
        #pragma unroll
        for (int kt = 0; kt < 2; ++kt) {
            const bf16x8 ah = *(const bf16x8*)&sHh[lrow][kt*32 + kg*8];
            const bf16x8 al = *(const bf16x8*)&sHl[lrow][kt*32 + kg*8];
            const bf16x8 bh = *(const bf16x8*)&sW4h[kt][lane][0];
            const bf16x8 bl = *(const bf16x8*)&sW4l[kt][lane][0];
            t = MFMA16(al, bh, t);
            t = MFMA16(ah, bl, t);
            t = MFMA16(ah, bh, t);
        }
        if (lr < 6) {
            const float b4c = b4[lr];
            #pragma unroll
            for (int rg = 0; rg < 4; ++rg)
                sLat[widx][kg*4 + rg][lr] = t[rg] + b4c;
        }
    }

    // ================= physics + scan: 8 passes x 2 rows =================
    const int half = lane >> 5;
    const int la   = lane & 31;
    const float i00 = kin[0], i01 = kin[1], i02 = kin[2];
    const float invRT = 1.0f / 2478.8191f;
    const float ksr0 = ((-kin[3]) * 96485.33f) * invRT;
    const float ksr1 = ((-kin[4]) * 96485.33f) * invRT;
    const float ksr2 = ((-kin[5]) * 96485.33f) * invRT;
    const float stepV = 1.25f / 999.0f;

    #pragma unroll 1
    for (int p = 0; p < 8; ++p) {
        const int rr  = p*2 + half;            // local row 0..15
        const int row = r0 + rr;
        const bool act = (row < B);

        float c0v = 0.0f, c1v = 0.0f, c2v = 0.0f, l0v = 0.0f, l1v = 0.0f;
        if (la == 0) {
            const int rowc = act ? row : (B - 1);
            const float* plat = &sLat[widx][rr][0];
            const float lat0 = plat[0], lat1 = plat[1], lat2 = plat[2];
            const float lat3 = plat[3], lat4 = plat[4], lat5 = plat[5];
            const float rrad = 4e-8f * __expf(lat0);
            const float epsv = frcp(1.0f + __expf(-lat1));
            const float zlt  = x[rowc*5 + 3];
            const float Lf   = zlt * frcp(1.0f - epsv);
            const float Kdl  = __expf(lat2);
            const float z0 = 2.0f*lat3, z1 = 2.0f*lat4, z2 = 2.0f*lat5;
            const float mz = fmaxf(z0, fmaxf(z1, z2));
            const float p0 = __expf(z0 - mz), p1 = __expf(z1 - mz), p2 = __expf(z2 - mz);
            const float ips = frcp(p0 + p1 + p2);
            const float th0 = p0*ips, th1 = p1*ips, th2 = p2*ips;
            const float irr = frcp(rrad);
            const float gdl   = (Kdl * 1.91e-9f) * (epsv * fsqrt(epsv)) * irr;
            const float asurf = (3.0f * (1.0f - epsv)) * Lf * irr;
            c0v = (i00*th0)*asurf; c1v = (i01*th1)*asurf; c2v = (i02*th2)*asurf;
            const float il0 = (((2.0f*96485.33f)*34.0f)*gdl)*0.1f;
            const float il1 = (((12.0f*96485.33f)*34.0f)*gdl)*0.1f;
            l0v = frcp(il0); l1v = frcp(il1);
        }
        const int src = half << 5;
        const float c0    = __shfl(c0v, src, 64);
        const float c1    = __shfl(c1v, src, 64);
        const float c2    = __shfl(c2v, src, 64);
        const float invl0 = __shfl(l0v, src, 64);
        const float invl1 = __shfl(l1v, src, 64);

        auto evaltot = [&](int v) -> float {
            const float V = -1.25f + stepV * (float)v;
            const float t0 = __expf(ksr0 * (V + 0.11f));
            const float t1 = __expf(ksr1 * (V - 0.08f));
            const float t2 = __expf(ksr2 * V);
            const float ie0 = frcp(frcp(c0*t0) + invl0);
            const float ie1 = frcp(frcp(c1*t1) + invl1);
            const float ie2 = c2*t2;       // i_lim[2] = inf
            return ie0 + ie1 + ie2;
        };

        // coarse: 32 points stride 32; i_tot weakly decreasing in v
        const int vc = la << 5;
        const float totc = evaltot(vc);
        float bd = fabsf(totc - 200.0f);
        int bidx = vc;

        const unsigned long long mall = __ballot(totc >= 200.0f);
        const unsigned int m32 = (unsigned int)(mall >> (half << 5));
        const int kstar = m32 ? (31 - __builtin_clz(m32)) : 0;
        const int base = kstar << 5;

        // fine: 32 points (base, base+32]
        {
            int vf = base + 1 + la;
            if (vf > NGRID-1) vf = NGRID-1;
            const float totf = evaltot(vf);
            const float df = fabsf(totf - 200.0f);
            if (df < bd || (df == bd && vf < bidx)) { bd = df; bidx = vf; }
        }

        // lexicographic (d, idx) butterfly within each 32-lane half
        #pragma unroll
        for (int off = 16; off; off >>= 1) {
            const float od = __shfl_xor(bd, off, 64);
            const int   oi = __shfl_xor(bidx, off, 64);
            if (od < bd || (od == bd && oi < bidx)) { bd = od; bidx = oi; }
        }

        // ---- select + FE ----
        const float V = -1.25f + stepV * (float)bidx;
        const float t0 = __expf(ksr0 * (V + 0.11f));
        const float t1 = __expf(ksr1 * (V - 0.08f));
        const float t2 = __expf(ksr2 * V);
        const float ie0 = frcp(frcp(c0*t0) + invl0);
        const float ie1 = frcp(frcp(c1*t1) + invl1);
        const float ie2 = c2*t2;
        const float itr = frcp(ie0 + ie1 + ie2);
        if (act && la < 2) {
            out[row*2 + la] = (la == 0) ? (ie1*itr) : (ie0*itr);
        }
    }
}

extern "C" void kernel_launch(void* const* d_in, const int* in_sizes, int n_in,
                              void* d_out, int out_size, void* d_ws, size_t ws_size,
                              hipStream_t stream) {
    const float* x   = (const float*)d_in[0];
    const float* W1  = (const float*)d_in[1];
    const float* b1  = (const float*)d_in[2];
    const float* W2  = (const float*)d_in[3];
    const float* b2  = (const float*)d_in[4];
    const float* W3  = (const float*)d_in[5];
    const float* b3  = (const float*)d_in[6];
    const float* W4  = (const float*)d_in[7];
    const float* b4  = (const float*)d_in[8];
    const float* kin = (const float*)d_in[9];
    float* out = (float*)d_out;
    const int B = in_sizes[0] / 5;

    // 64 rows per block (4 waves x 16 rows): B=16384 -> 256 blocks
    // = 1 block/CU, 1 wave/SIMD; MLP via split-bf16 MFMA, ~64 KB LDS.
    const int grid = (B + 63) / 64;
    ph_kernel<<<grid, BLOCK, 0, stream>>>(x, W1, b1, W2, b2, W3, b3, W4, b4, kin, out, B);
}

// Round 12
// 16.456 us; speedup vs baseline: 1.5273x; 1.0941x over previous
//
#include <hip/hip_runtime.h>
#include <math.h>

#define NGRID 1000
#define BLOCK 256
#define WPB 4          // waves per block; each wave owns 16 rows -> 64 rows/block

typedef __attribute__((ext_vector_type(8))) __bf16 bf16x8;
typedef __attribute__((ext_vector_type(4))) float  f32x4;

__device__ __forceinline__ float frcp(float x)  { return __builtin_amdgcn_rcpf(x); }
__device__ __forceinline__ float fsqrt(float x) { return __builtin_amdgcn_sqrtf(x); }

#define MFMA16(A,Bv,C) __builtin_amdgcn_mfma_f32_16x16x32_bf16((A),(Bv),(C),0,0,0)

// split v into bf16 hi (RTNE cast) + bf16 lo (residual), by value
__device__ __forceinline__ __bf16 bhi(float v) { return (__bf16)v; }
__device__ __forceinline__ __bf16 blo(float v, __bf16 hi) {
    return (__bf16)(v - (float)hi);
}

__global__ __launch_bounds__(BLOCK) void ph_kernel(
    const float* __restrict__ x,
    const float* __restrict__ W1, const float* __restrict__ b1,
    const float* __restrict__ W2, const float* __restrict__ b2,
    const float* __restrict__ W3, const float* __restrict__ b3,
    const float* __restrict__ W4, const float* __restrict__ b4,
    const float* __restrict__ kin,
    float* __restrict__ out, int B)
{
    // weight fragments in MFMA-frag-ready order: [nt][kt][lane][e] -> b128/lane
    __shared__ __attribute__((aligned(16))) __bf16 sW1h[4][64][8],    sW1l[4][64][8];
    __shared__ __attribute__((aligned(16))) __bf16 sW2h[4][2][64][8], sW2l[4][2][64][8];
    __shared__ __attribute__((aligned(16))) __bf16 sW3h[4][2][64][8], sW3l[4][2][64][8];
    __shared__ __attribute__((aligned(16))) __bf16 sW4h[2][64][8],    sW4l[2][64][8];
    // h planes between layers: [local row][k], stride 72 (144B) kills b128 conflicts
    __shared__ __attribute__((aligned(16))) __bf16 sHh[64][72], sHl[64][72];
    __shared__ float sLat[WPB][16][8];
    __shared__ float sPhy[WPB][16][6];   // c0,c1,c2,invl0,invl1 per row

    const int tid  = threadIdx.x;
    const int lane = tid & 63;
    const int widx = tid >> 6;
    const int lr   = lane & 15;     // A-row / B-col / C-col within 16-tile
    const int kg   = lane >> 4;     // k-group (8 k's per group)
    const int r0   = blockIdx.x * 64 + widx * 16;   // wave's first row

    // ---- x fragments for layer 1 (before barrier; independent of LDS) ----
    bf16x8 xh, xl;
    {
        int xrow = r0 + lr; if (xrow > B-1) xrow = B-1;
        #pragma unroll
        for (int e = 0; e < 8; ++e) {
            float v = 0.0f;
            if (kg == 0 && e < 5) v = x[xrow*5 + e];
            const __bf16 hi = bhi(v);
            xh[e] = hi;
            xl[e] = blo(v, hi);
        }
    }

    // ================= stage weight fragments (frag-ready layout) ==========
    {
        const int nt  = widx;            // each wave quarter handles one ntile
        const int col = nt*16 + lr;
        bf16x8 h8, l8;
        #pragma unroll
        for (int e = 0; e < 8; ++e) {
            const int k = kg*8 + e;
            float v = 0.0f;
            if (k < 5) v = W1[k*64 + col];
            const __bf16 hi = bhi(v);
            h8[e] = hi;
            l8[e] = blo(v, hi);
        }
        *(bf16x8*)&sW1h[nt][lane][0] = h8;
        *(bf16x8*)&sW1l[nt][lane][0] = l8;

        #pragma unroll
        for (int kt = 0; kt < 2; ++kt) {
            bf16x8 h2, l2, h3, l3;
            #pragma unroll
            for (int e = 0; e < 8; ++e) {
                const int k = kt*32 + kg*8 + e;
                const float v2 = W2[k*64 + col];
                const float v3 = W3[k*64 + col];
                const __bf16 hi2 = bhi(v2);
                const __bf16 hi3 = bhi(v3);
                h2[e] = hi2; l2[e] = blo(v2, hi2);
                h3[e] = hi3; l3[e] = blo(v3, hi3);
            }
            *(bf16x8*)&sW2h[nt][kt][lane][0] = h2;
            *(bf16x8*)&sW2l[nt][kt][lane][0] = l2;
            *(bf16x8*)&sW3h[nt][kt][lane][0] = h3;
            *(bf16x8*)&sW3l[nt][kt][lane][0] = l3;
        }
        if (widx == 0) {                 // W4 (64x6): ntile 0 only, cols>=6 zero
            #pragma unroll
            for (int kt = 0; kt < 2; ++kt) {
                bf16x8 h4, l4;
                #pragma unroll
                for (int e = 0; e < 8; ++e) {
                    const int k = kt*32 + kg*8 + e;
                    float v = 0.0f;
                    if (lr < 6) v = W4[k*6 + lr];
                    const __bf16 hi = bhi(v);
                    h4[e] = hi;
                    l4[e] = blo(v, hi);
                }
                *(bf16x8*)&sW4h[kt][lane][0] = h4;
                *(bf16x8*)&sW4l[kt][lane][0] = l4;
            }
        }
    }
    __syncthreads();   // the only block-wide barrier

    const f32x4 zz = {0.0f, 0.0f, 0.0f, 0.0f};
    f32x4 acc[4];

    // ================= layer 1: x(16x5 pad32) @ W1 =================
    #pragma unroll
    for (int nt = 0; nt < 4; ++nt) {
        const bf16x8 bh = *(const bf16x8*)&sW1h[nt][lane][0];
        const bf16x8 bl = *(const bf16x8*)&sW1l[nt][lane][0];
        f32x4 t = MFMA16(xl, bh, zz);
        t = MFMA16(xh, bl, t);
        acc[nt] = MFMA16(xh, bh, t);
    }
    #pragma unroll
    for (int nt = 0; nt < 4; ++nt) {
        const float bb = b1[nt*16 + lr];
        #pragma unroll
        for (int rg = 0; rg < 4; ++rg) {
            float v = fmaxf(acc[nt][rg] + bb, 0.0f);
            const int row = widx*16 + kg*4 + rg;
            const __bf16 hi = bhi(v);
            sHh[row][nt*16 + lr] = hi;
            sHl[row][nt*16 + lr] = blo(v, hi);
        }
    }

    // ================= layers 2,3: h(16x64) @ W =================
    #pragma unroll
    for (int L = 0; L < 2; ++L) {
        const int lrow = widx*16 + lr;
        bf16x8 ah[2], al[2];
        #pragma unroll
        for (int kt = 0; kt < 2; ++kt) {
            ah[kt] = *(const bf16x8*)&sHh[lrow][kt*32 + kg*8];
            al[kt] = *(const bf16x8*)&sHl[lrow][kt*32 + kg*8];
        }
        #pragma unroll
        for (int nt = 0; nt < 4; ++nt) {
            f32x4 t = zz;
            #pragma unroll
            for (int kt = 0; kt < 2; ++kt) {
                const bf16x8 bh = (L == 0) ? *(const bf16x8*)&sW2h[nt][kt][lane][0]
                                           : *(const bf16x8*)&sW3h[nt][kt][lane][0];
                const bf16x8 bl = (L == 0) ? *(const bf16x8*)&sW2l[nt][kt][lane][0]
                                           : *(const bf16x8*)&sW3l[nt][kt][lane][0];
                t = MFMA16(al[kt], bh, t);
                t = MFMA16(ah[kt], bl, t);
                t = MFMA16(ah[kt], bh, t);
            }
            acc[nt] = t;
        }
        const float* bp = (L == 0) ? b2 : b3;
        #pragma unroll
        for (int nt = 0; nt < 4; ++nt) {
            const float bb = bp[nt*16 + lr];
            #pragma unroll
            for (int rg = 0; rg < 4; ++rg) {
                float v = fmaxf(acc[nt][rg] + bb, 0.0f);
                const int row = widx*16 + kg*4 + rg;
                const __bf16 hi = bhi(v);
                sHh[row][nt*16 + lr] = hi;   // in-place: all reads already done
                sHl[row][nt*16 + lr] = blo(v, hi);
            }
        }
    }

    // ================= layer 4: h(16x64) @ W4 -> sLat =================
    {
        const int lrow = widx*16 + lr;
        f32x4 t = zz;
        #pragma unroll
        for (int kt = 0; kt < 2; ++kt) {
            const bf16x8 ah = *(const bf16x8*)&sHh[lrow][kt*32 + kg*8];
            const bf16x8 al = *(const bf16x8*)&sHl[lrow][kt*32 + kg*8];
            const bf16x8 bh = *(const bf16x8*)&sW4h[kt][lane][0];
            const bf16x8 bl = *(const bf16x8*)&sW4l[kt][lane][0];
            t = MFMA16(al, bh, t);
            t = MFMA16(ah, bl, t);
            t = MFMA16(ah, bh, t);
        }
        if (lr < 6) {
            const float b4c = b4[lr];
            #pragma unroll
            for (int rg = 0; rg < 4; ++rg)
                sLat[widx][kg*4 + rg][lr] = t[rg] + b4c;
        }
    }

    // ======== physics for all 16 rows in parallel (lane&15 -> row) ========
    // All 64 lanes compute (4x redundant across kg), kg==0 lanes store.
    const float i00 = kin[0], i01 = kin[1], i02 = kin[2];
    const float invRT = 1.0f / 2478.8191f;
    const float ksr0 = ((-kin[3]) * 96485.33f) * invRT;
    const float ksr1 = ((-kin[4]) * 96485.33f) * invRT;
    const float ksr2 = ((-kin[5]) * 96485.33f) * invRT;
    const float stepV = 1.25f / 999.0f;

    {
        const int prow = (r0 + lr < B) ? (r0 + lr) : (B - 1);
        const float* plat = &sLat[widx][lr][0];
        const float lat0 = plat[0], lat1 = plat[1], lat2 = plat[2];
        const float lat3 = plat[3], lat4 = plat[4], lat5 = plat[5];
        const float rrad = 4e-8f * __expf(lat0);
        const float epsv = frcp(1.0f + __expf(-lat1));
        const float zlt  = x[prow*5 + 3];
        const float Lf   = zlt * frcp(1.0f - epsv);
        const float Kdl  = __expf(lat2);
        const float z0 = 2.0f*lat3, z1 = 2.0f*lat4, z2 = 2.0f*lat5;
        const float mz = fmaxf(z0, fmaxf(z1, z2));
        const float p0 = __expf(z0 - mz), p1 = __expf(z1 - mz), p2 = __expf(z2 - mz);
        const float ips = frcp(p0 + p1 + p2);
        const float th0 = p0*ips, th1 = p1*ips, th2 = p2*ips;
        const float irr = frcp(rrad);
        const float gdl   = (Kdl * 1.91e-9f) * (epsv * fsqrt(epsv)) * irr;
        const float asurf = (3.0f * (1.0f - epsv)) * Lf * irr;
        const float c0v = (i00*th0)*asurf;
        const float c1v = (i01*th1)*asurf;
        const float c2v = (i02*th2)*asurf;
        const float il0 = (((2.0f*96485.33f)*34.0f)*gdl)*0.1f;
        const float il1 = (((12.0f*96485.33f)*34.0f)*gdl)*0.1f;
        if (kg == 0) {
            sPhy[widx][lr][0] = c0v;
            sPhy[widx][lr][1] = c1v;
            sPhy[widx][lr][2] = c2v;
            sPhy[widx][lr][3] = frcp(il0);
            sPhy[widx][lr][4] = frcp(il1);
        }
    }
    // wave-local write -> read: in-order per wave, no barrier needed

    // ================= scan: 8 passes x 2 rows =================
    const int half = lane >> 5;
    const int la   = lane & 31;

    #pragma unroll 1
    for (int p = 0; p < 8; ++p) {
        const int rr  = p*2 + half;            // local row 0..15
        const int row = r0 + rr;
        const bool act = (row < B);

        // row constants via LDS broadcast (2 addresses per wave)
        const float c0    = sPhy[widx][rr][0];
        const float c1    = sPhy[widx][rr][1];
        const float c2    = sPhy[widx][rr][2];
        const float invl0 = sPhy[widx][rr][3];
        const float invl1 = sPhy[widx][rr][4];

        auto evaltot = [&](int v) -> float {
            const float V = -1.25f + stepV * (float)v;
            const float t0 = __expf(ksr0 * (V + 0.11f));
            const float t1 = __expf(ksr1 * (V - 0.08f));
            const float t2 = __expf(ksr2 * V);
            const float ie0 = frcp(frcp(c0*t0) + invl0);
            const float ie1 = frcp(frcp(c1*t1) + invl1);
            const float ie2 = c2*t2;       // i_lim[2] = inf
            return ie0 + ie1 + ie2;
        };

        // coarse: 32 points stride 32; i_tot weakly decreasing in v
        const int vc = la << 5;
        const float totc = evaltot(vc);
        float bd = fabsf(totc - 200.0f);
        int bidx = vc;

        const unsigned long long mall = __ballot(totc >= 200.0f);
        const unsigned int m32 = (unsigned int)(mall >> (half << 5));
        const int kstar = m32 ? (31 - __builtin_clz(m32)) : 0;
        const int base = kstar << 5;

        // fine: 32 points (base, base+32]
        {
            int vf = base + 1 + la;
            if (vf > NGRID-1) vf = NGRID-1;
            const float totf = evaltot(vf);
            const float df = fabsf(totf - 200.0f);
            if (df < bd || (df == bd && vf < bidx)) { bd = df; bidx = vf; }
        }

        // lexicographic (d, idx) butterfly within each 32-lane half
        #pragma unroll
        for (int off = 16; off; off >>= 1) {
            const float od = __shfl_xor(bd, off, 64);
            const int   oi = __shfl_xor(bidx, off, 64);
            if (od < bd || (od == bd && oi < bidx)) { bd = od; bidx = oi; }
        }

        // ---- select + FE ----
        const float V = -1.25f + stepV * (float)bidx;
        const float t0 = __expf(ksr0 * (V + 0.11f));
        const float t1 = __expf(ksr1 * (V - 0.08f));
        const float t2 = __expf(ksr2 * V);
        const float ie0 = frcp(frcp(c0*t0) + invl0);
        const float ie1 = frcp(frcp(c1*t1) + invl1);
        const float ie2 = c2*t2;
        const float itr = frcp(ie0 + ie1 + ie2);
        if (act && la < 2) {
            out[row*2 + la] = (la == 0) ? (ie1*itr) : (ie0*itr);
        }
    }
}

extern "C" void kernel_launch(void* const* d_in, const int* in_sizes, int n_in,
                              void* d_out, int out_size, void* d_ws, size_t ws_size,
                              hipStream_t stream) {
    const float* x   = (const float*)d_in[0];
    const float* W1  = (const float*)d_in[1];
    const float* b1  = (const float*)d_in[2];
    const float* W2  = (const float*)d_in[3];
    const float* b2  = (const float*)d_in[4];
    const float* W3  = (const float*)d_in[5];
    const float* b3  = (const float*)d_in[6];
    const float* W4  = (const float*)d_in[7];
    const float* b4  = (const float*)d_in[8];
    const float* kin = (const float*)d_in[9];
    float* out = (float*)d_out;
    const int B = in_sizes[0] / 5;

    // 64 rows per block (4 waves x 16 rows): B=16384 -> 256 blocks
    // = 1 block/CU, 1 wave/SIMD; MLP via split-bf16 MFMA, ~65 KB LDS.
    const int grid = (B + 63) / 64;
    ph_kernel<<<grid, BLOCK, 0, stream>>>(x, W1, b1, W2, b2, W3, b3, W4, b4, kin, out, B);
}

// Round 14
// 13.853 us; speedup vs baseline: 1.8143x; 1.1880x over previous
//
#include <hip/hip_runtime.h>
#include <math.h>

#define NGRID 1000
#define BLOCK 512      // 8 waves: 0-3 = MFMA MLP (16 rows each), all 8 scan 8 rows

typedef __attribute__((ext_vector_type(8))) __bf16 bf16x8;
typedef __attribute__((ext_vector_type(4))) float  f32x4;

__device__ __forceinline__ float frcp(float x)  { return __builtin_amdgcn_rcpf(x); }
__device__ __forceinline__ float fsqrt(float x) { return __builtin_amdgcn_sqrtf(x); }

#define MFMA16(A,Bv,C) __builtin_amdgcn_mfma_f32_16x16x32_bf16((A),(Bv),(C),0,0,0)

// split v into bf16 hi (RTNE cast) + bf16 lo (residual), by value
__device__ __forceinline__ __bf16 bhi(float v) { return (__bf16)v; }
__device__ __forceinline__ __bf16 blo(float v, __bf16 hi) {
    return (__bf16)(v - (float)hi);
}

__global__ __launch_bounds__(BLOCK) void ph_kernel(
    const float* __restrict__ x,
    const float* __restrict__ W1, const float* __restrict__ b1,
    const float* __restrict__ W2, const float* __restrict__ b2,
    const float* __restrict__ W3, const float* __restrict__ b3,
    const float* __restrict__ W4, const float* __restrict__ b4,
    const float* __restrict__ kin,
    float* __restrict__ out, int B)
{
    // weight fragments in MFMA-frag-ready order: [nt][kt][lane][e] -> b128/lane
    __shared__ __attribute__((aligned(16))) __bf16 sW1h[4][64][8],    sW1l[4][64][8];
    __shared__ __attribute__((aligned(16))) __bf16 sW2h[4][2][64][8], sW2l[4][2][64][8];
    __shared__ __attribute__((aligned(16))) __bf16 sW3h[4][2][64][8], sW3l[4][2][64][8];
    __shared__ __attribute__((aligned(16))) __bf16 sW4h[2][64][8],    sW4l[2][64][8];
    // h planes: [block row 0..63][k], stride 72 (144B) kills b128 conflicts
    __shared__ __attribute__((aligned(16))) __bf16 sHh[64][72], sHl[64][72];
    __shared__ float sLat[64][8];
    __shared__ float sPhy[64][6];   // c0,c1,c2,invl0,invl1 per block row

    const int tid  = threadIdx.x;
    const int lane = tid & 63;
    const int widx = tid >> 6;      // 0..7
    const int lr   = lane & 15;     // A-row / B-col / C-col within 16-tile
    const int kg   = lane >> 4;     // k-group (8 k's per group)
    const int br0  = blockIdx.x * 64;              // block's first row

    // ============== stage weight fragments, split across 8 waves ==========
    if (widx < 4) {
        const int nt  = widx;
        const int col = nt*16 + lr;
        bf16x8 h8, l8;
        #pragma unroll
        for (int e = 0; e < 8; ++e) {
            const int k = kg*8 + e;
            float v = 0.0f;
            if (k < 5) v = W1[k*64 + col];
            const __bf16 hi = bhi(v);
            h8[e] = hi;
            l8[e] = blo(v, hi);
        }
        *(bf16x8*)&sW1h[nt][lane][0] = h8;
        *(bf16x8*)&sW1l[nt][lane][0] = l8;

        #pragma unroll
        for (int kt = 0; kt < 2; ++kt) {
            bf16x8 h2, l2;
            #pragma unroll
            for (int e = 0; e < 8; ++e) {
                const int k = kt*32 + kg*8 + e;
                const float v2 = W2[k*64 + col];
                const __bf16 hi2 = bhi(v2);
                h2[e] = hi2; l2[e] = blo(v2, hi2);
            }
            *(bf16x8*)&sW2h[nt][kt][lane][0] = h2;
            *(bf16x8*)&sW2l[nt][kt][lane][0] = l2;
        }
    } else {
        const int nt  = widx - 4;
        const int col = nt*16 + lr;
        #pragma unroll
        for (int kt = 0; kt < 2; ++kt) {
            bf16x8 h3, l3;
            #pragma unroll
            for (int e = 0; e < 8; ++e) {
                const int k = kt*32 + kg*8 + e;
                const float v3 = W3[k*64 + col];
                const __bf16 hi3 = bhi(v3);
                h3[e] = hi3; l3[e] = blo(v3, hi3);
            }
            *(bf16x8*)&sW3h[nt][kt][lane][0] = h3;
            *(bf16x8*)&sW3l[nt][kt][lane][0] = l3;
        }
        if (widx == 4) {                 // W4 (64x6): cols>=6 zero
            #pragma unroll
            for (int kt = 0; kt < 2; ++kt) {
                bf16x8 h4, l4;
                #pragma unroll
                for (int e = 0; e < 8; ++e) {
                    const int k = kt*32 + kg*8 + e;
                    float v = 0.0f;
                    if (lr < 6) v = W4[k*6 + lr];
                    const __bf16 hi = bhi(v);
                    h4[e] = hi;
                    l4[e] = blo(v, hi);
                }
                *(bf16x8*)&sW4h[kt][lane][0] = h4;
                *(bf16x8*)&sW4l[kt][lane][0] = l4;
            }
        }
    }
    __syncthreads();   // barrier 1: weights staged

    // ================= MLP on waves 0-3 (R12-verbatim tiling) =============
    if (widx < 4) {
        const int r0 = br0 + widx * 16;     // wave's first row

        bf16x8 xh, xl;
        {
            int xrow = r0 + lr; if (xrow > B-1) xrow = B-1;
            #pragma unroll
            for (int e = 0; e < 8; ++e) {
                float v = 0.0f;
                if (kg == 0 && e < 5) v = x[xrow*5 + e];
                const __bf16 hi = bhi(v);
                xh[e] = hi;
                xl[e] = blo(v, hi);
            }
        }

        const f32x4 zz = {0.0f, 0.0f, 0.0f, 0.0f};
        f32x4 acc[4];

        // ---- layer 1: x(16x5 pad32) @ W1 ----
        #pragma unroll
        for (int nt = 0; nt < 4; ++nt) {
            const bf16x8 bh = *(const bf16x8*)&sW1h[nt][lane][0];
            const bf16x8 bl = *(const bf16x8*)&sW1l[nt][lane][0];
            f32x4 t = MFMA16(xl, bh, zz);
            t = MFMA16(xh, bl, t);
            acc[nt] = MFMA16(xh, bh, t);
        }
        #pragma unroll
        for (int nt = 0; nt < 4; ++nt) {
            const float bb = b1[nt*16 + lr];
            #pragma unroll
            for (int rg = 0; rg < 4; ++rg) {
                float v = fmaxf(acc[nt][rg] + bb, 0.0f);
                const int row = widx*16 + kg*4 + rg;
                const __bf16 hi = bhi(v);
                sHh[row][nt*16 + lr] = hi;
                sHl[row][nt*16 + lr] = blo(v, hi);
            }
        }

        // ---- layers 2,3: h(16x64) @ W ----
        #pragma unroll
        for (int L = 0; L < 2; ++L) {
            const int lrow = widx*16 + lr;
            bf16x8 ah[2], al[2];
            #pragma unroll
            for (int kt = 0; kt < 2; ++kt) {
                ah[kt] = *(const bf16x8*)&sHh[lrow][kt*32 + kg*8];
                al[kt] = *(const bf16x8*)&sHl[lrow][kt*32 + kg*8];
            }
            #pragma unroll
            for (int nt = 0; nt < 4; ++nt) {
                f32x4 t = zz;
                #pragma unroll
                for (int kt = 0; kt < 2; ++kt) {
                    const bf16x8 bh = (L == 0) ? *(const bf16x8*)&sW2h[nt][kt][lane][0]
                                               : *(const bf16x8*)&sW3h[nt][kt][lane][0];
                    const bf16x8 bl = (L == 0) ? *(const bf16x8*)&sW2l[nt][kt][lane][0]
                                               : *(const bf16x8*)&sW3l[nt][kt][lane][0];
                    t = MFMA16(al[kt], bh, t);
                    t = MFMA16(ah[kt], bl, t);
                    t = MFMA16(ah[kt], bh, t);
                }
                acc[nt] = t;
            }
            const float* bp = (L == 0) ? b2 : b3;
            #pragma unroll
            for (int nt = 0; nt < 4; ++nt) {
                const float bb = bp[nt*16 + lr];
                #pragma unroll
                for (int rg = 0; rg < 4; ++rg) {
                    float v = fmaxf(acc[nt][rg] + bb, 0.0f);
                    const int row = widx*16 + kg*4 + rg;
                    const __bf16 hi = bhi(v);
                    sHh[row][nt*16 + lr] = hi;   // in-place: reads already done
                    sHl[row][nt*16 + lr] = blo(v, hi);
                }
            }
        }

        // ---- layer 4: h(16x64) @ W4 -> sLat ----
        {
            const int lrow = widx*16 + lr;
            f32x4 t = zz;
            #pragma unroll
            for (int kt = 0; kt < 2; ++kt) {
                const bf16x8 ah = *(const bf16x8*)&sHh[lrow][kt*32 + kg*8];
                const bf16x8 al = *(const bf16x8*)&sHl[lrow][kt*32 + kg*8];
                const bf16x8 bh = *(const bf16x8*)&sW4h[kt][lane][0];
                const bf16x8 bl = *(const bf16x8*)&sW4l[kt][lane][0];
                t = MFMA16(al, bh, t);
                t = MFMA16(ah, bl, t);
                t = MFMA16(ah, bh, t);
            }
            if (lr < 6) {
                const float b4c = b4[lr];
                #pragma unroll
                for (int rg = 0; rg < 4; ++rg)
                    sLat[widx*16 + kg*4 + rg][lr] = t[rg] + b4c;
            }
        }
    }
    __syncthreads();   // barrier 2: latents ready for all 8 waves

    // ======== physics: all 8 waves, wave w owns block rows w*8..w*8+7 ======
    const int lr8 = lr & 7;
    const float i00 = kin[0], i01 = kin[1], i02 = kin[2];
    const float invRT = 1.0f / 2478.8191f;
    const float ksr0 = ((-kin[3]) * 96485.33f) * invRT;
    const float ksr1 = ((-kin[4]) * 96485.33f) * invRT;
    const float ksr2 = ((-kin[5]) * 96485.33f) * invRT;
    const float stepV = 1.25f / 999.0f;

    {
        const int brow = widx*8 + lr8;                 // block row 0..63
        const int prow = (br0 + brow < B) ? (br0 + brow) : (B - 1);
        const float* plat = &sLat[brow][0];
        const float lat0 = plat[0], lat1 = plat[1], lat2 = plat[2];
        const float lat3 = plat[3], lat4 = plat[4], lat5 = plat[5];
        const float rrad = 4e-8f * __expf(lat0);
        const float epsv = frcp(1.0f + __expf(-lat1));
        const float zlt  = x[prow*5 + 3];
        const float Lf   = zlt * frcp(1.0f - epsv);
        const float Kdl  = __expf(lat2);
        const float z0 = 2.0f*lat3, z1 = 2.0f*lat4, z2 = 2.0f*lat5;
        const float mz = fmaxf(z0, fmaxf(z1, z2));
        const float p0 = __expf(z0 - mz), p1 = __expf(z1 - mz), p2 = __expf(z2 - mz);
        const float ips = frcp(p0 + p1 + p2);
        const float th0 = p0*ips, th1 = p1*ips, th2 = p2*ips;
        const float irr = frcp(rrad);
        const float gdl   = (Kdl * 1.91e-9f) * (epsv * fsqrt(epsv)) * irr;
        const float asurf = (3.0f * (1.0f - epsv)) * Lf * irr;
        const float c0v = (i00*th0)*asurf;
        const float c1v = (i01*th1)*asurf;
        const float c2v = (i02*th2)*asurf;
        const float il0 = (((2.0f*96485.33f)*34.0f)*gdl)*0.1f;
        const float il1 = (((12.0f*96485.33f)*34.0f)*gdl)*0.1f;
        if (kg == 0 && lr < 8) {
            sPhy[brow][0] = c0v;
            sPhy[brow][1] = c1v;
            sPhy[brow][2] = c2v;
            sPhy[brow][3] = frcp(il0);
            sPhy[brow][4] = frcp(il1);
        }
    }
    // wave-local write -> read (each wave reads only its own 8 rows)

    // ================= scan: 4 passes x 2 rows per wave =================
    const int half = lane >> 5;
    const int la   = lane & 31;

    #pragma unroll 1
    for (int p = 0; p < 4; ++p) {
        const int brow = widx*8 + p*2 + half;  // block row 0..63
        const int row  = br0 + brow;
        const bool act = (row < B);

        const float c0    = sPhy[brow][0];
        const float c1    = sPhy[brow][1];
        const float c2    = sPhy[brow][2];
        const float invl0 = sPhy[brow][3];
        const float invl1 = sPhy[brow][4];

        auto evaltot = [&](int v) -> float {
            const float V = -1.25f + stepV * (float)v;
            const float t0 = __expf(ksr0 * (V + 0.11f));
            const float t1 = __expf(ksr1 * (V - 0.08f));
            const float t2 = __expf(ksr2 * V);
            const float ie0 = frcp(frcp(c0*t0) + invl0);
            const float ie1 = frcp(frcp(c1*t1) + invl1);
            const float ie2 = c2*t2;       // i_lim[2] = inf
            return ie0 + ie1 + ie2;
        };

        // coarse: 32 points stride 32; i_tot weakly decreasing in v
        const int vc = la << 5;
        const float totc = evaltot(vc);
        float bd = fabsf(totc - 200.0f);
        int bidx = vc;

        const unsigned long long mall = __ballot(totc >= 200.0f);
        const unsigned int m32 = (unsigned int)(mall >> (half << 5));
        const int kstar = m32 ? (31 - __builtin_clz(m32)) : 0;
        const int base = kstar << 5;

        // fine: 32 points (base, base+32]
        {
            int vf = base + 1 + la;
            if (vf > NGRID-1) vf = NGRID-1;
            const float totf = evaltot(vf);
            const float df = fabsf(totf - 200.0f);
            if (df < bd || (df == bd && vf < bidx)) { bd = df; bidx = vf; }
        }

        // lexicographic (d, idx) butterfly within each 32-lane half
        #pragma unroll
        for (int off = 16; off; off >>= 1) {
            const float od = __shfl_xor(bd, off, 64);
            const int   oi = __shfl_xor(bidx, off, 64);
            if (od < bd || (od == bd && oi < bidx)) { bd = od; bidx = oi; }
        }

        // ---- select + FE ----
        const float V = -1.25f + stepV * (float)bidx;
        const float t0 = __expf(ksr0 * (V + 0.11f));
        const float t1 = __expf(ksr1 * (V - 0.08f));
        const float t2 = __expf(ksr2 * V);
        const float ie0 = frcp(frcp(c0*t0) + invl0);
        const float ie1 = frcp(frcp(c1*t1) + invl1);
        const float ie2 = c2*t2;
        const float itr = frcp(ie0 + ie1 + ie2);
        if (act && la < 2) {
            out[row*2 + la] = (la == 0) ? (ie1*itr) : (ie0*itr);
        }
    }
}

extern "C" void kernel_launch(void* const* d_in, const int* in_sizes, int n_in,
                              void* d_out, int out_size, void* d_ws, size_t ws_size,
                              hipStream_t stream) {
    const float* x   = (const float*)d_in[0];
    const float* W1  = (const float*)d_in[1];
    const float* b1  = (const float*)d_in[2];
    const float* W2  = (const float*)d_in[3];
    const float* b2  = (const float*)d_in[4];
    const float* W3  = (const float*)d_in[5];
    const float* b3  = (const float*)d_in[6];
    const float* W4  = (const float*)d_in[7];
    const float* b4  = (const float*)d_in[8];
    const float* kin = (const float*)d_in[9];
    float* out = (float*)d_out;
    const int B = in_sizes[0] / 5;

    // 64 rows per block, 8 waves: waves 0-3 MFMA-MLP (R12 tiling verbatim),
    // all 8 waves split physics+scan (8 rows each). 256 blocks = 1/CU.
    const int grid = (B + 63) / 64;
    ph_kernel<<<grid, BLOCK, 0, stream>>>(x, W1, b1, W2, b2, W3, b3, W4, b4, kin, out, B);
}

// Round 15
// 13.834 us; speedup vs baseline: 1.8167x; 1.0013x over previous
//
#include <hip/hip_runtime.h>
#include <math.h>

#define NGRID 1000
#define BLOCK 512      // 8 waves: 0-1 = MFMA MLP (16 rows each), all 8 scan 4 rows

typedef __attribute__((ext_vector_type(8))) __bf16 bf16x8;
typedef __attribute__((ext_vector_type(4))) float  f32x4;

__device__ __forceinline__ float frcp(float x)  { return __builtin_amdgcn_rcpf(x); }
__device__ __forceinline__ float fsqrt(float x) { return __builtin_amdgcn_sqrtf(x); }

#define MFMA16(A,Bv,C) __builtin_amdgcn_mfma_f32_16x16x32_bf16((A),(Bv),(C),0,0,0)

// split v into bf16 hi (RTNE cast) + bf16 lo (residual), by value
__device__ __forceinline__ __bf16 bhi(float v) { return (__bf16)v; }
__device__ __forceinline__ __bf16 blo(float v, __bf16 hi) {
    return (__bf16)(v - (float)hi);
}

__global__ __launch_bounds__(BLOCK) void ph_kernel(
    const float* __restrict__ x,
    const float* __restrict__ W1, const float* __restrict__ b1,
    const float* __restrict__ W2, const float* __restrict__ b2,
    const float* __restrict__ W3, const float* __restrict__ b3,
    const float* __restrict__ W4, const float* __restrict__ b4,
    const float* __restrict__ kin,
    float* __restrict__ out, int B)
{
    // weight fragments in MFMA-frag-ready order: [nt][kt][lane][e] -> b128/lane
    __shared__ __attribute__((aligned(16))) __bf16 sW1h[4][64][8],    sW1l[4][64][8];
    __shared__ __attribute__((aligned(16))) __bf16 sW2h[4][2][64][8], sW2l[4][2][64][8];
    __shared__ __attribute__((aligned(16))) __bf16 sW3h[4][2][64][8], sW3l[4][2][64][8];
    __shared__ __attribute__((aligned(16))) __bf16 sW4h[2][64][8],    sW4l[2][64][8];
    // h planes: [block row 0..31][k], stride 72 (144B) kills b128 conflicts
    __shared__ __attribute__((aligned(16))) __bf16 sHh[32][72], sHl[32][72];
    __shared__ float sLat[32][8];
    __shared__ float sPhy[32][6];   // c0,c1,c2,invl0,invl1 per block row

    const int tid  = threadIdx.x;
    const int lane = tid & 63;
    const int widx = tid >> 6;      // 0..7
    const int lr   = lane & 15;     // A-row / B-col / C-col within 16-tile
    const int kg   = lane >> 4;     // k-group (8 k's per group)
    const int br0  = blockIdx.x * 32;              // block's first row

    // ============== stage weight fragments, split across 8 waves ==========
    if (widx < 4) {
        const int nt  = widx;
        const int col = nt*16 + lr;
        bf16x8 h8, l8;
        #pragma unroll
        for (int e = 0; e < 8; ++e) {
            const int k = kg*8 + e;
            float v = 0.0f;
            if (k < 5) v = W1[k*64 + col];
            const __bf16 hi = bhi(v);
            h8[e] = hi;
            l8[e] = blo(v, hi);
        }
        *(bf16x8*)&sW1h[nt][lane][0] = h8;
        *(bf16x8*)&sW1l[nt][lane][0] = l8;

        #pragma unroll
        for (int kt = 0; kt < 2; ++kt) {
            bf16x8 h2, l2;
            #pragma unroll
            for (int e = 0; e < 8; ++e) {
                const int k = kt*32 + kg*8 + e;
                const float v2 = W2[k*64 + col];
                const __bf16 hi2 = bhi(v2);
                h2[e] = hi2; l2[e] = blo(v2, hi2);
            }
            *(bf16x8*)&sW2h[nt][kt][lane][0] = h2;
            *(bf16x8*)&sW2l[nt][kt][lane][0] = l2;
        }
    } else {
        const int nt  = widx - 4;
        const int col = nt*16 + lr;
        #pragma unroll
        for (int kt = 0; kt < 2; ++kt) {
            bf16x8 h3, l3;
            #pragma unroll
            for (int e = 0; e < 8; ++e) {
                const int k = kt*32 + kg*8 + e;
                const float v3 = W3[k*64 + col];
                const __bf16 hi3 = bhi(v3);
                h3[e] = hi3; l3[e] = blo(v3, hi3);
            }
            *(bf16x8*)&sW3h[nt][kt][lane][0] = h3;
            *(bf16x8*)&sW3l[nt][kt][lane][0] = l3;
        }
        if (widx == 4) {                 // W4 (64x6): cols>=6 zero
            #pragma unroll
            for (int kt = 0; kt < 2; ++kt) {
                bf16x8 h4, l4;
                #pragma unroll
                for (int e = 0; e < 8; ++e) {
                    const int k = kt*32 + kg*8 + e;
                    float v = 0.0f;
                    if (lr < 6) v = W4[k*6 + lr];
                    const __bf16 hi = bhi(v);
                    h4[e] = hi;
                    l4[e] = blo(v, hi);
                }
                *(bf16x8*)&sW4h[kt][lane][0] = h4;
                *(bf16x8*)&sW4l[kt][lane][0] = l4;
            }
        }
    }
    __syncthreads();   // barrier 1: weights staged

    // ================= MLP on waves 0-1 (R12-verbatim tiling) =============
    if (widx < 2) {
        const int r0 = br0 + widx * 16;     // wave's first row

        bf16x8 xh, xl;
        {
            int xrow = r0 + lr; if (xrow > B-1) xrow = B-1;
            #pragma unroll
            for (int e = 0; e < 8; ++e) {
                float v = 0.0f;
                if (kg == 0 && e < 5) v = x[xrow*5 + e];
                const __bf16 hi = bhi(v);
                xh[e] = hi;
                xl[e] = blo(v, hi);
            }
        }

        const f32x4 zz = {0.0f, 0.0f, 0.0f, 0.0f};
        f32x4 acc[4];

        // ---- layer 1: x(16x5 pad32) @ W1 ----
        #pragma unroll
        for (int nt = 0; nt < 4; ++nt) {
            const bf16x8 bh = *(const bf16x8*)&sW1h[nt][lane][0];
            const bf16x8 bl = *(const bf16x8*)&sW1l[nt][lane][0];
            f32x4 t = MFMA16(xl, bh, zz);
            t = MFMA16(xh, bl, t);
            acc[nt] = MFMA16(xh, bh, t);
        }
        #pragma unroll
        for (int nt = 0; nt < 4; ++nt) {
            const float bb = b1[nt*16 + lr];
            #pragma unroll
            for (int rg = 0; rg < 4; ++rg) {
                float v = fmaxf(acc[nt][rg] + bb, 0.0f);
                const int row = widx*16 + kg*4 + rg;
                const __bf16 hi = bhi(v);
                sHh[row][nt*16 + lr] = hi;
                sHl[row][nt*16 + lr] = blo(v, hi);
            }
        }

        // ---- layers 2,3: h(16x64) @ W ----
        #pragma unroll
        for (int L = 0; L < 2; ++L) {
            const int lrow = widx*16 + lr;
            bf16x8 ah[2], al[2];
            #pragma unroll
            for (int kt = 0; kt < 2; ++kt) {
                ah[kt] = *(const bf16x8*)&sHh[lrow][kt*32 + kg*8];
                al[kt] = *(const bf16x8*)&sHl[lrow][kt*32 + kg*8];
            }
            #pragma unroll
            for (int nt = 0; nt < 4; ++nt) {
                f32x4 t = zz;
                #pragma unroll
                for (int kt = 0; kt < 2; ++kt) {
                    const bf16x8 bh = (L == 0) ? *(const bf16x8*)&sW2h[nt][kt][lane][0]
                                               : *(const bf16x8*)&sW3h[nt][kt][lane][0];
                    const bf16x8 bl = (L == 0) ? *(const bf16x8*)&sW2l[nt][kt][lane][0]
                                               : *(const bf16x8*)&sW3l[nt][kt][lane][0];
                    t = MFMA16(al[kt], bh, t);
                    t = MFMA16(ah[kt], bl, t);
                    t = MFMA16(ah[kt], bh, t);
                }
                acc[nt] = t;
            }
            const float* bp = (L == 0) ? b2 : b3;
            #pragma unroll
            for (int nt = 0; nt < 4; ++nt) {
                const float bb = bp[nt*16 + lr];
                #pragma unroll
                for (int rg = 0; rg < 4; ++rg) {
                    float v = fmaxf(acc[nt][rg] + bb, 0.0f);
                    const int row = widx*16 + kg*4 + rg;
                    const __bf16 hi = bhi(v);
                    sHh[row][nt*16 + lr] = hi;   // in-place: reads already done
                    sHl[row][nt*16 + lr] = blo(v, hi);
                }
            }
        }

        // ---- layer 4: h(16x64) @ W4 -> sLat ----
        {
            const int lrow = widx*16 + lr;
            f32x4 t = zz;
            #pragma unroll
            for (int kt = 0; kt < 2; ++kt) {
                const bf16x8 ah = *(const bf16x8*)&sHh[lrow][kt*32 + kg*8];
                const bf16x8 al = *(const bf16x8*)&sHl[lrow][kt*32 + kg*8];
                const bf16x8 bh = *(const bf16x8*)&sW4h[kt][lane][0];
                const bf16x8 bl = *(const bf16x8*)&sW4l[kt][lane][0];
                t = MFMA16(al, bh, t);
                t = MFMA16(ah, bl, t);
                t = MFMA16(ah, bh, t);
            }
            if (lr < 6) {
                const float b4c = b4[lr];
                #pragma unroll
                for (int rg = 0; rg < 4; ++rg)
                    sLat[widx*16 + kg*4 + rg][lr] = t[rg] + b4c;
            }
        }
    }
    __syncthreads();   // barrier 2: latents ready for all 8 waves

    // ======== physics: all 8 waves, wave w owns block rows w*4..w*4+3 ======
    const int lr4 = lr & 3;
    const float i00 = kin[0], i01 = kin[1], i02 = kin[2];
    const float invRT = 1.0f / 2478.8191f;
    const float ksr0 = ((-kin[3]) * 96485.33f) * invRT;
    const float ksr1 = ((-kin[4]) * 96485.33f) * invRT;
    const float ksr2 = ((-kin[5]) * 96485.33f) * invRT;
    const float stepV = 1.25f / 999.0f;

    {
        const int brow = widx*4 + lr4;                 // block row 0..31
        const int prow = (br0 + brow < B) ? (br0 + brow) : (B - 1);
        const float* plat = &sLat[brow][0];
        const float lat0 = plat[0], lat1 = plat[1], lat2 = plat[2];
        const float lat3 = plat[3], lat4 = plat[4], lat5 = plat[5];
        const float rrad = 4e-8f * __expf(lat0);
        const float epsv = frcp(1.0f + __expf(-lat1));
        const float zlt  = x[prow*5 + 3];
        const float Lf   = zlt * frcp(1.0f - epsv);
        const float Kdl  = __expf(lat2);
        const float z0 = 2.0f*lat3, z1 = 2.0f*lat4, z2 = 2.0f*lat5;
        const float mz = fmaxf(z0, fmaxf(z1, z2));
        const float p0 = __expf(z0 - mz), p1 = __expf(z1 - mz), p2 = __expf(z2 - mz);
        const float ips = frcp(p0 + p1 + p2);
        const float th0 = p0*ips, th1 = p1*ips, th2 = p2*ips;
        const float irr = frcp(rrad);
        const float gdl   = (Kdl * 1.91e-9f) * (epsv * fsqrt(epsv)) * irr;
        const float asurf = (3.0f * (1.0f - epsv)) * Lf * irr;
        const float c0v = (i00*th0)*asurf;
        const float c1v = (i01*th1)*asurf;
        const float c2v = (i02*th2)*asurf;
        const float il0 = (((2.0f*96485.33f)*34.0f)*gdl)*0.1f;
        const float il1 = (((12.0f*96485.33f)*34.0f)*gdl)*0.1f;
        if (kg == 0 && lr < 4) {
            sPhy[brow][0] = c0v;
            sPhy[brow][1] = c1v;
            sPhy[brow][2] = c2v;
            sPhy[brow][3] = frcp(il0);
            sPhy[brow][4] = frcp(il1);
        }
    }
    // wave-local write -> read (each wave reads only its own 4 rows)

    // ================= scan: 2 passes x 2 rows per wave =================
    const int half = lane >> 5;
    const int la   = lane & 31;

    #pragma unroll 1
    for (int p = 0; p < 2; ++p) {
        const int brow = widx*4 + p*2 + half;  // block row 0..31
        const int row  = br0 + brow;
        const bool act = (row < B);

        const float c0    = sPhy[brow][0];
        const float c1    = sPhy[brow][1];
        const float c2    = sPhy[brow][2];
        const float invl0 = sPhy[brow][3];
        const float invl1 = sPhy[brow][4];

        auto evaltot = [&](int v) -> float {
            const float V = -1.25f + stepV * (float)v;
            const float t0 = __expf(ksr0 * (V + 0.11f));
            const float t1 = __expf(ksr1 * (V - 0.08f));
            const float t2 = __expf(ksr2 * V);
            const float ie0 = frcp(frcp(c0*t0) + invl0);
            const float ie1 = frcp(frcp(c1*t1) + invl1);
            const float ie2 = c2*t2;       // i_lim[2] = inf
            return ie0 + ie1 + ie2;
        };

        // coarse: 32 points stride 32; i_tot weakly decreasing in v
        const int vc = la << 5;
        const float totc = evaltot(vc);
        float bd = fabsf(totc - 200.0f);
        int bidx = vc;

        const unsigned long long mall = __ballot(totc >= 200.0f);
        const unsigned int m32 = (unsigned int)(mall >> (half << 5));
        const int kstar = m32 ? (31 - __builtin_clz(m32)) : 0;
        const int base = kstar << 5;

        // fine: 32 points (base, base+32]
        {
            int vf = base + 1 + la;
            if (vf > NGRID-1) vf = NGRID-1;
            const float totf = evaltot(vf);
            const float df = fabsf(totf - 200.0f);
            if (df < bd || (df == bd && vf < bidx)) { bd = df; bidx = vf; }
        }

        // lexicographic (d, idx) butterfly within each 32-lane half
        #pragma unroll
        for (int off = 16; off; off >>= 1) {
            const float od = __shfl_xor(bd, off, 64);
            const int   oi = __shfl_xor(bidx, off, 64);
            if (od < bd || (od == bd && oi < bidx)) { bd = od; bidx = oi; }
        }

        // ---- select + FE ----
        const float V = -1.25f + stepV * (float)bidx;
        const float t0 = __expf(ksr0 * (V + 0.11f));
        const float t1 = __expf(ksr1 * (V - 0.08f));
        const float t2 = __expf(ksr2 * V);
        const float ie0 = frcp(frcp(c0*t0) + invl0);
        const float ie1 = frcp(frcp(c1*t1) + invl1);
        const float ie2 = c2*t2;
        const float itr = frcp(ie0 + ie1 + ie2);
        if (act && la < 2) {
            out[row*2 + la] = (la == 0) ? (ie1*itr) : (ie0*itr);
        }
    }
}

extern "C" void kernel_launch(void* const* d_in, const int* in_sizes, int n_in,
                              void* d_out, int out_size, void* d_ws, size_t ws_size,
                              hipStream_t stream) {
    const float* x   = (const float*)d_in[0];
    const float* W1  = (const float*)d_in[1];
    const float* b1  = (const float*)d_in[2];
    const float* W2  = (const float*)d_in[3];
    const float* b2  = (const float*)d_in[4];
    const float* W3  = (const float*)d_in[5];
    const float* b3  = (const float*)d_in[6];
    const float* W4  = (const float*)d_in[7];
    const float* b4  = (const float*)d_in[8];
    const float* kin = (const float*)d_in[9];
    float* out = (float*)d_out;
    const int B = in_sizes[0] / 5;

    // 32 rows per block, 8 waves: waves 0-1 MFMA-MLP (R12 tiling verbatim),
    // all 8 waves split physics+scan (4 rows each, 2 passes).
    // 512 blocks x ~55 KB LDS = exactly 2 resident blocks/CU = 4 waves/SIMD.
    const int grid = (B + 31) / 32;
    ph_kernel<<<grid, BLOCK, 0, stream>>>(x, W1, b1, W2, b2, W3, b3, W4, b4, kin, out, B);
}